// Round 2
// baseline (378.315 us; speedup 1.0000x reference)
//
#include <hip/hip_runtime.h>
#include <cstddef>

// CSWinBlock on MI355X — round 5: weight B-fragments loaded DIRECTLY from global (L2-resident
// bf16 planes) instead of LDS staging. Removes ws buffer from k_projmlp (LDS 67.5->33.5 KB,
// 2->3 blocks/CU) and all weight-staging barriers; compiler pipelines the global loads
// against MFMA with counted vmcnt. k_ln_qkv gets the same treatment (Cs separate buffer).
// ws layout (<= 97 MB used):
//   [0, 32MB)    q-plane  bf16 [NTOK][128]  — attention(+LePE) output written IN-PLACE here
//   [32, 64MB)   k-plane  bf16 [NTOK][128]
//   [64, 96MB)   v-plane  bf16 [NTOK][128]
//   [96MB, +384KB) bf16 weights: wqkv[49152] wproj[16384] w1[65536] w2[65536]

#define LDIM 16384
#define NTOK 131072
#define PLANE ((size_t)NTOK * 128)

typedef __attribute__((ext_vector_type(8))) short bf16x8;
typedef __attribute__((ext_vector_type(4))) float f32x4;

__device__ __forceinline__ unsigned short f2bf(float f) {
  union { float f; unsigned int i; } u; u.f = f;
  unsigned int r = u.i + 0x7fffu + ((u.i >> 16) & 1u);
  return (unsigned short)(r >> 16);
}
__device__ __forceinline__ float bflo(unsigned int u) {
  union { unsigned int i; float f; } x; x.i = u << 16; return x.f;
}
__device__ __forceinline__ float bfhi(unsigned int u) {
  union { unsigned int i; float f; } x; x.i = u & 0xffff0000u; return x.f;
}
__device__ __forceinline__ unsigned int pk(float a, float b) {
  return (unsigned)f2bf(a) | ((unsigned)f2bf(b) << 16);
}

// async 16B global->LDS (wave-uniform LDS base + lane*16)
__device__ __forceinline__ void async16(const unsigned short* g, unsigned short* l) {
  __builtin_amdgcn_global_load_lds(
      (const __attribute__((address_space(1))) unsigned int*)g,
      (__attribute__((address_space(3))) unsigned int*)l, 16, 0, 0);
}

// swizzled tile: element (row, col) lives at row*128 + ((col/8)^(row&7))*8 + col%8
__device__ __forceinline__ bf16x8 fragS(const unsigned short* base, int row, int c) {
  return *(const bf16x8*)(base + row * 128 + ((c ^ (row & 7)) << 3));
}

// direct global bf16x8 (one global_load_dwordx4)
__device__ __forceinline__ bf16x8 ldw(const unsigned short* p) {
  return *(const bf16x8*)p;
}

// stage 64x128 bf16 tile global->LDS via async copies, swizzled layout
__device__ __forceinline__ void stageS64(const unsigned short* __restrict__ src,
                                         unsigned short* dst, int tid) {
  const int lane = tid & 63, wv = tid >> 6;
  #pragma unroll
  for (int i = 0; i < 4; i++) {
    const int base = i * 256 + wv * 64;
    const int f = base + lane;
    const int row = f >> 4, cs = f & 15, cg = cs ^ (row & 7);
    async16(src + (size_t)row * 128 + (cg << 3), dst + (size_t)base * 8);
  }
}

// C frags -> swizzled LDS -> coalesced bf16 global store (2x2 wave decomposition)
__device__ __forceinline__ void storeC(f32x4 acc[4][4], unsigned short* Cs,
                                       unsigned short* __restrict__ dst, int dstStride, int tid) {
  const int wv = tid >> 6, lane = tid & 63, q = lane >> 4, r = lane & 15;
  const int wm = wv & 1, wn = wv >> 1;
  #pragma unroll
  for (int mt = 0; mt < 4; mt++)
    #pragma unroll
    for (int nt = 0; nt < 4; nt++) {
      const int col = wn * 64 + nt * 16 + r;
      #pragma unroll
      for (int rg = 0; rg < 4; rg++) {
        const int row = wm * 64 + mt * 16 + q * 4 + rg;
        Cs[row * 128 + ((((col >> 3) ^ (row & 7)) << 3) | (col & 7))] = f2bf(acc[mt][nt][rg]);
      }
    }
  __syncthreads();
  #pragma unroll
  for (int i = 0; i < 8; i++) {
    const int f = tid + i * 256;
    const int row = f >> 4, cs = f & 15, cg = cs ^ (row & 7);
    *(uint4*)(dst + (size_t)row * dstStride + (cg << 3)) = *(const uint4*)(Cs + row * 128 + cs * 8);
  }
}

// gelu tanh-approx: x*sigmoid(1.59576912*(x+0.044715x^3)) = x*rcp(1+exp2(-k*(...)))
__device__ __forceinline__ float gelu_t(float x) {
  const float y = -2.3022083f * (x + 0.044715f * x * x * x);  // -1.59576912*log2(e)*(...)
  const float p = __builtin_amdgcn_exp2f(y);
  return x * __builtin_amdgcn_rcpf(1.f + p);
}

// ================= Kernel 0: weights fp32 -> bf16 =================
__global__ void k_prep(const float* __restrict__ wq, const float* __restrict__ wp,
                       const float* __restrict__ w1, const float* __restrict__ w2,
                       unsigned short* __restrict__ wb)
{
  const int id = blockIdx.x * 256 + threadIdx.x;   // 49152 threads, 4 elems each
  const float* src; int off;
  if (id < 12288)      { src = wq; off = id; }
  else if (id < 16384) { src = wp; off = id - 12288; }
  else if (id < 32768) { src = w1; off = id - 16384; }
  else                 { src = w2; off = id - 32768; }
  const float4 v = *(const float4*)(src + (size_t)off * 4);
  uint2 u; u.x = pk(v.x, v.y); u.y = pk(v.z, v.w);
  *(uint2*)(wb + (size_t)id * 4) = u;
}

// ================= Kernel 1: LN1 + QKV GEMM (weights direct from global) =================
__global__ __launch_bounds__(256, 2) void k_ln_qkv(
    const float* __restrict__ x, const float* __restrict__ g, const float* __restrict__ bb,
    const unsigned short* __restrict__ wqkvb, unsigned short* __restrict__ qkv)
{
  __shared__ unsigned short xs[128 * 128];
  __shared__ unsigned short Cs[128 * 128];
  __shared__ float redS[128][2], redQ[128][2];
  const int tid = threadIdx.x;
  const long m0 = (long)blockIdx.x * 128;
  { // LN: 2 threads/row
    const int m = tid >> 1, hf = tid & 1;
    const float4* xg = (const float4*)(x + (size_t)(m0 + m) * 128 + hf * 64);
    float4 xv[16];
    #pragma unroll
    for (int i = 0; i < 16; i++) xv[i] = xg[i];
    float s1 = 0.f, s2 = 0.f;
    #pragma unroll
    for (int i = 0; i < 16; i++) {
      s1 += xv[i].x + xv[i].y + xv[i].z + xv[i].w;
      s2 += xv[i].x * xv[i].x + xv[i].y * xv[i].y + xv[i].z * xv[i].z + xv[i].w * xv[i].w;
    }
    redS[m][hf] = s1; redQ[m][hf] = s2;
    __syncthreads();
    const float mean = (redS[m][0] + redS[m][1]) * (1.f / 128.f);
    const float var  = (redQ[m][0] + redQ[m][1]) * (1.f / 128.f) - mean * mean;
    const float rs = rsqrtf(var + 1e-5f);
    const float4* g4 = (const float4*)(g + hf * 64);
    const float4* b4 = (const float4*)(bb + hf * 64);
    #pragma unroll
    for (int i = 0; i < 8; i++) {
      float4 v0 = xv[2 * i], v1 = xv[2 * i + 1];
      float4 g0 = g4[2 * i], g1 = g4[2 * i + 1], p0 = b4[2 * i], p1 = b4[2 * i + 1];
      uint4 u;
      u.x = pk((v0.x - mean) * rs * g0.x + p0.x, (v0.y - mean) * rs * g0.y + p0.y);
      u.y = pk((v0.z - mean) * rs * g0.z + p0.z, (v0.w - mean) * rs * g0.w + p0.w);
      u.z = pk((v1.x - mean) * rs * g1.x + p1.x, (v1.y - mean) * rs * g1.y + p1.y);
      u.w = pk((v1.z - mean) * rs * g1.z + p1.z, (v1.w - mean) * rs * g1.w + p1.w);
      const int c = hf * 8 + i;
      *(uint4*)&xs[m * 128 + ((c ^ (m & 7)) << 3)] = u;
    }
  }
  const int lane = tid & 63, q = lane >> 4, r = lane & 15;
  const int wv = tid >> 6, wm = wv & 1, wn = wv >> 1;
  __syncthreads();                             // xs ready
  for (int nc = 0; nc < 3; nc++) {
    f32x4 acc[4][4];
    #pragma unroll
    for (int a = 0; a < 4; a++)
      #pragma unroll
      for (int b = 0; b < 4; b++) acc[a][b] = f32x4{0.f, 0.f, 0.f, 0.f};
    const unsigned short* wbase = wqkvb + (size_t)(nc * 128 + wn * 64) * 128;
    #pragma unroll
    for (int kc = 0; kc < 4; kc++) {
      bf16x8 a[4], b[4];
      #pragma unroll
      for (int mt = 0; mt < 4; mt++) a[mt] = fragS(xs, wm * 64 + mt * 16 + r, kc * 4 + q);
      #pragma unroll
      for (int nt = 0; nt < 4; nt++) b[nt] = ldw(wbase + (nt * 16 + r) * 128 + kc * 32 + q * 8);
      #pragma unroll
      for (int mt = 0; mt < 4; mt++)
        #pragma unroll
        for (int nt = 0; nt < 4; nt++)
          acc[mt][nt] = __builtin_amdgcn_mfma_f32_16x16x32_bf16(a[mt], b[nt], acc[mt][nt], 0, 0, 0);
    }
    if (nc) __syncthreads();                   // prior Cs readout done
    storeC(acc, Cs, qkv + (size_t)nc * PLANE + (size_t)m0 * 128, 128, tid);
  }
}

// ================= Kernel 2: CSWin attention + fused LePE (in-place into q-plane) ==========
__global__ __launch_bounds__(256, 2) void k_attn(
    const unsigned short* __restrict__ qkv,
    const float* __restrict__ conv_w0, const float* __restrict__ conv_b0,
    const float* __restrict__ conv_w1, const float* __restrict__ conv_b1,
    unsigned short* __restrict__ att)
{
  __shared__ unsigned short Kt[256][40];
  __shared__ unsigned short Vt[32][264];
  __shared__ unsigned short Ps[4][64][72];
  const unsigned short* kpl = qkv + PLANE;
  const unsigned short* vpl = qkv + 2 * PLANE;
  const int t = threadIdx.x;
  const int win = blockIdx.x, head = blockIdx.y, br = blockIdx.z;
  const int bimg = win >> 6, widx = win & 63;
  const int c0 = br * 64 + head * 32;
  const int lgWs = (br == 0) ? 1 : 7;
  const int Wsm1 = (1 << lgWs) - 1;
  const long base = (long)bimg * LDIM + ((br == 0) ? widx * 2 : widx * 256);

  { // stage K + V^T (thread t = key t)
    const long tj = base + (long)(t >> lgWs) * 128 + (t & Wsm1);
    const uint4* kp = (const uint4*)(kpl + (size_t)tj * 128 + c0);
    uint4 k0v = kp[0], k1v = kp[1], k2v = kp[2], k3v = kp[3];
    *(uint4*)&Kt[t][0]  = k0v;  *(uint4*)&Kt[t][8]  = k1v;
    *(uint4*)&Kt[t][16] = k2v;  *(uint4*)&Kt[t][24] = k3v;
    const uint4* vp = (const uint4*)(vpl + (size_t)tj * 128 + c0);
    uint4 vv[4] = {vp[0], vp[1], vp[2], vp[3]};
    const unsigned short* vs = (const unsigned short*)vv;
    #pragma unroll
    for (int d = 0; d < 32; d++) Vt[d][t] = vs[d];
  }
  const int wave = t >> 6, lane = t & 63, q = lane >> 4, r = lane & 15;
  const int qbase = wave * 64;
  bf16x8 qf[4];
  #pragma unroll
  for (int mt = 0; mt < 4; mt++) {
    const int row = qbase + mt * 16 + r;
    const long tok = base + (long)(row >> lgWs) * 128 + (row & Wsm1);
    qf[mt] = *(const bf16x8*)(qkv + (size_t)tok * 128 + c0 + q * 8);
  }
  __syncthreads();

  const float factor = 0.17677669529663687f * 1.44269504088896341f;
  f32x4 Oacc[4][2];
  float psum[4][4];
  #pragma unroll
  for (int mt = 0; mt < 4; mt++) {
    Oacc[mt][0] = f32x4{0.f, 0.f, 0.f, 0.f};
    Oacc[mt][1] = f32x4{0.f, 0.f, 0.f, 0.f};
    #pragma unroll
    for (int rg = 0; rg < 4; rg++) psum[mt][rg] = 0.f;
  }

  for (int kc = 0; kc < 4; kc++) {
    bf16x8 kb[4];
    #pragma unroll
    for (int nt = 0; nt < 4; nt++) kb[nt] = *(const bf16x8*)&Kt[kc * 64 + nt * 16 + r][q * 8];
    f32x4 s[4][4];
    #pragma unroll
    for (int mt = 0; mt < 4; mt++)
      #pragma unroll
      for (int nt = 0; nt < 4; nt++) {
        f32x4 z = f32x4{0.f, 0.f, 0.f, 0.f};
        s[mt][nt] = __builtin_amdgcn_mfma_f32_16x16x32_bf16(qf[mt], kb[nt], z, 0, 0, 0);
      }
    #pragma unroll
    for (int mt = 0; mt < 4; mt++)
      #pragma unroll
      for (int nt = 0; nt < 4; nt++)
        #pragma unroll
        for (int rg = 0; rg < 4; rg++) {
          const float p = __builtin_amdgcn_exp2f(s[mt][nt][rg] * factor);   // max-free
          psum[mt][rg] += p;
          Ps[wave][mt * 16 + q * 4 + rg][nt * 16 + r] = f2bf(p);
        }
    #pragma unroll
    for (int kst = 0; kst < 2; kst++) {
      bf16x8 pa[4], vb[2];
      #pragma unroll
      for (int mt = 0; mt < 4; mt++) pa[mt] = *(const bf16x8*)&Ps[wave][mt * 16 + r][kst * 32 + q * 8];
      #pragma unroll
      for (int nto = 0; nto < 2; nto++) vb[nto] = *(const bf16x8*)&Vt[nto * 16 + r][kc * 64 + kst * 32 + q * 8];
      #pragma unroll
      for (int mt = 0; mt < 4; mt++)
        #pragma unroll
        for (int nto = 0; nto < 2; nto++)
          Oacc[mt][nto] = __builtin_amdgcn_mfma_f32_16x16x32_bf16(pa[mt], vb[nto], Oacc[mt][nto], 0, 0, 0);
    }
  }

  #pragma unroll
  for (int mt = 0; mt < 4; mt++)
    #pragma unroll
    for (int rg = 0; rg < 4; rg++) {
      float v = psum[mt][rg];
      v += __shfl_xor(v, 1); v += __shfl_xor(v, 2);
      v += __shfl_xor(v, 4); v += __shfl_xor(v, 8);
      psum[mt][rg] = __builtin_amdgcn_rcpf(v);
    }

  // ---- fused LePE: depthwise 3x3 over the window, V already staged in Vt ----
  const float* cw = br ? conv_w1 : conv_w0;
  const float* cb = br ? conv_b1 : conv_b0;
  float wle[2][9], ble[2];
  #pragma unroll
  for (int nto = 0; nto < 2; nto++) {
    const int ch = head * 32 + nto * 16 + r;      // channel within branch (0..63)
    ble[nto] = cb[ch];
    #pragma unroll
    for (int tp = 0; tp < 9; tp++) wle[nto][tp] = cw[ch * 9 + tp];
  }
  const int WsW = 1 << lgWs;          // 2 (br0) or 128 (br1)
  const int HsW = 256 >> lgWs;        // 128 (br0) or 2 (br1)

  #pragma unroll
  for (int mt = 0; mt < 4; mt++)
    #pragma unroll
    for (int rg = 0; rg < 4; rg++) {
      const int row = qbase + mt * 16 + q * 4 + rg;      // window token 0..255
      const int ii = row >> lgWs, jj = row & Wsm1;
      const long tok = base + (long)ii * 128 + jj;
      float lep0 = ble[0], lep1 = ble[1];
      #pragma unroll
      for (int di = -1; di <= 1; di++) {
        if ((unsigned)(ii + di) >= (unsigned)HsW) continue;
        #pragma unroll
        for (int dj = -1; dj <= 1; dj++) {
          if ((unsigned)(jj + dj) >= (unsigned)WsW) continue;
          const int nb = row + di * WsW + dj;            // neighbor window token
          const int tap = (di + 1) * 3 + (dj + 1);
          lep0 = fmaf(bflo(Vt[r][nb]),      wle[0][tap], lep0);
          lep1 = fmaf(bflo(Vt[16 + r][nb]), wle[1][tap], lep1);
        }
      }
      const float pr = psum[mt][rg];
      att[(size_t)tok * 128 + c0 + r]      = f2bf(Oacc[mt][0][rg] * pr + lep0);
      att[(size_t)tok * 128 + c0 + 16 + r] = f2bf(Oacc[mt][1][rg] * pr + lep1);
    }
}

// ========== Kernel 3: fused proj + residual + LN2 + FFN1 + GELU + FFN2 + residual ==========
// All weight B-fragments loaded directly from global (L2-resident bf16 planes).
// LDS = hs(16K) + xs(16K) + red(2K) -> 3 blocks/CU.
__global__ __launch_bounds__(256, 3) void k_projmlp(
    const unsigned short* __restrict__ att, const unsigned short* __restrict__ wprojb,
    const float* __restrict__ b_proj, const float* __restrict__ x,
    const float* __restrict__ g, const float* __restrict__ bb,
    const unsigned short* __restrict__ w1b, const unsigned short* __restrict__ w2b,
    const float* __restrict__ b1, const float* __restrict__ b2,
    float* __restrict__ out)
{
  __shared__ unsigned short hs[64 * 128];   // att tile (proj A), later gelu(h)
  __shared__ unsigned short xs[64 * 128];   // LN2 output (bf16, swizzled)
  __shared__ float redS[64][4], redQ[64][4];
  const int tid = threadIdx.x;
  const long m0 = (long)blockIdx.x * 64;
  const int lane = tid & 63, q = lane >> 4, r = lane & 15, wv = tid >> 6;

  stageS64(att + (size_t)m0 * 128, hs, tid);

  // hoisted residual/param loads — independent of the staging above
  float xv[4][2][4];
  #pragma unroll
  for (int mt = 0; mt < 4; mt++)
    #pragma unroll
    for (int nt = 0; nt < 2; nt++) {
      const int col = wv * 32 + nt * 16 + r;
      #pragma unroll
      for (int rg = 0; rg < 4; rg++)
        xv[mt][nt][rg] = x[(size_t)(m0 + mt * 16 + q * 4 + rg) * 128 + col];
    }
  float bpv[2], gv[2], bv2[2];
  #pragma unroll
  for (int nt = 0; nt < 2; nt++) {
    const int col = wv * 32 + nt * 16 + r;
    bpv[nt] = b_proj[col]; gv[nt] = g[col]; bv2[nt] = bb[col];
  }
  __syncthreads();                                 // hs (att tile) ready

  // ---- proj GEMM: rows mt*16+q*4+rg (0..63), cols wv*32+nt*16+r; B direct from global
  f32x4 xres[4][2];
  #pragma unroll
  for (int mt = 0; mt < 4; mt++) { xres[mt][0] = f32x4{0.f,0.f,0.f,0.f}; xres[mt][1] = f32x4{0.f,0.f,0.f,0.f}; }
  {
    const unsigned short* wpbase = wprojb + (size_t)(wv * 32) * 128;
    #pragma unroll
    for (int kc = 0; kc < 4; kc++) {
      bf16x8 a[4], b[2];
      #pragma unroll
      for (int mt = 0; mt < 4; mt++) a[mt] = fragS(hs, mt * 16 + r, kc * 4 + q);
      #pragma unroll
      for (int nt = 0; nt < 2; nt++) b[nt] = ldw(wpbase + (nt * 16 + r) * 128 + kc * 32 + q * 8);
      #pragma unroll
      for (int mt = 0; mt < 4; mt++)
        #pragma unroll
        for (int nt = 0; nt < 2; nt++)
          xres[mt][nt] = __builtin_amdgcn_mfma_f32_16x16x32_bf16(a[mt], b[nt], xres[mt][nt], 0, 0, 0);
    }
  }
  // residual add
  #pragma unroll
  for (int mt = 0; mt < 4; mt++)
    #pragma unroll
    for (int nt = 0; nt < 2; nt++)
      #pragma unroll
      for (int rg = 0; rg < 4; rg++)
        xres[mt][nt][rg] += xv[mt][nt][rg] + bpv[nt];

  // ---- LN2 stats: per-row sums (wave covers 32 cols -> shfl over r, cross-wave via LDS)
  #pragma unroll
  for (int mt = 0; mt < 4; mt++)
    #pragma unroll
    for (int rg = 0; rg < 4; rg++) {
      float s1 = xres[mt][0][rg] + xres[mt][1][rg];
      float s2 = xres[mt][0][rg] * xres[mt][0][rg] + xres[mt][1][rg] * xres[mt][1][rg];
      s1 += __shfl_xor(s1, 1); s1 += __shfl_xor(s1, 2); s1 += __shfl_xor(s1, 4); s1 += __shfl_xor(s1, 8);
      s2 += __shfl_xor(s2, 1); s2 += __shfl_xor(s2, 2); s2 += __shfl_xor(s2, 4); s2 += __shfl_xor(s2, 8);
      if (r == 0) { const int row = mt * 16 + q * 4 + rg; redS[row][wv] = s1; redQ[row][wv] = s2; }
    }
  __syncthreads();                                 // red ready
  #pragma unroll
  for (int mt = 0; mt < 4; mt++)
    #pragma unroll
    for (int rg = 0; rg < 4; rg++) {
      const int row = mt * 16 + q * 4 + rg;
      const float s1 = redS[row][0] + redS[row][1] + redS[row][2] + redS[row][3];
      const float s2 = redQ[row][0] + redQ[row][1] + redQ[row][2] + redQ[row][3];
      const float mean = s1 * (1.f / 128.f);
      const float var  = s2 * (1.f / 128.f) - mean * mean;
      const float rs = rsqrtf(var + 1e-5f);
      #pragma unroll
      for (int nt = 0; nt < 2; nt++) {
        const int col = wv * 32 + nt * 16 + r;
        const float v = (xres[mt][nt][rg] - mean) * rs * gv[nt] + bv2[nt];
        xs[row * 128 + ((((col >> 3) ^ (row & 7)) << 3) | (col & 7))] = f2bf(v);
      }
    }

  // ---- MLP: 4 Dff chunks of 128; weights direct from global
  f32x4 oacc[4][2];
  #pragma unroll
  for (int mt = 0; mt < 4; mt++) { oacc[mt][0] = f32x4{0.f,0.f,0.f,0.f}; oacc[mt][1] = f32x4{0.f,0.f,0.f,0.f}; }

  for (int nc = 0; nc < 4; nc++) {
    __syncthreads();                               // xs ready (nc=0) / hs reads done (nc>0)
    f32x4 h[4][2];
    #pragma unroll
    for (int mt = 0; mt < 4; mt++) { h[mt][0] = f32x4{0.f,0.f,0.f,0.f}; h[mt][1] = f32x4{0.f,0.f,0.f,0.f}; }
    {
      const unsigned short* w1base = w1b + (size_t)(nc * 128 + wv * 32) * 128;
      #pragma unroll
      for (int kc = 0; kc < 4; kc++) {
        bf16x8 a[4], b[2];
        #pragma unroll
        for (int mt = 0; mt < 4; mt++) a[mt] = fragS(xs, mt * 16 + r, kc * 4 + q);
        #pragma unroll
        for (int nt = 0; nt < 2; nt++) b[nt] = ldw(w1base + (nt * 16 + r) * 128 + kc * 32 + q * 8);
        #pragma unroll
        for (int mt = 0; mt < 4; mt++)
          #pragma unroll
          for (int nt = 0; nt < 2; nt++)
            h[mt][nt] = __builtin_amdgcn_mfma_f32_16x16x32_bf16(a[mt], b[nt], h[mt][nt], 0, 0, 0);
      }
    }
    #pragma unroll
    for (int mt = 0; mt < 4; mt++)
      #pragma unroll
      for (int nt = 0; nt < 2; nt++) {
        const int col = wv * 32 + nt * 16 + r;
        const float bv = b1[nc * 128 + col];
        #pragma unroll
        for (int rg = 0; rg < 4; rg++) {
          const int rw = mt * 16 + q * 4 + rg;
          hs[rw * 128 + ((((col >> 3) ^ (rw & 7)) << 3) | (col & 7))] = f2bf(gelu_t(h[mt][nt][rg] + bv));
        }
      }
    __syncthreads();                               // hs = gelu(h) ready
    {
      const unsigned short* w2base = w2b + (size_t)(wv * 32) * 512 + nc * 128;
      #pragma unroll
      for (int kc = 0; kc < 4; kc++) {
        bf16x8 a[4], b[2];
        #pragma unroll
        for (int mt = 0; mt < 4; mt++) a[mt] = fragS(hs, mt * 16 + r, kc * 4 + q);
        #pragma unroll
        for (int nt = 0; nt < 2; nt++) b[nt] = ldw(w2base + (nt * 16 + r) * 512 + kc * 32 + q * 8);
        #pragma unroll
        for (int mt = 0; mt < 4; mt++)
          #pragma unroll
          for (int nt = 0; nt < 2; nt++)
            oacc[mt][nt] = __builtin_amdgcn_mfma_f32_16x16x32_bf16(a[mt], b[nt], oacc[mt][nt], 0, 0, 0);
      }
    }
  }
  // ---- epilogue: out = xres + b2 + mlp  (single write, no out-read)
  #pragma unroll
  for (int mt = 0; mt < 4; mt++)
    #pragma unroll
    for (int nt = 0; nt < 2; nt++) {
      const int col = wv * 32 + nt * 16 + r;
      const float bv = b2[col];
      #pragma unroll
      for (int rg = 0; rg < 4; rg++) {
        const size_t idx = (size_t)(m0 + mt * 16 + q * 4 + rg) * 128 + col;
        out[idx] = xres[mt][nt][rg] + bv + oacc[mt][nt][rg];
      }
    }
}

extern "C" void kernel_launch(void* const* d_in, const int* in_sizes, int n_in,
                              void* d_out, int out_size, void* d_ws, size_t ws_size,
                              hipStream_t stream) {
  const float* x       = (const float*)d_in[0];
  const float* ln1_g   = (const float*)d_in[1];
  const float* ln1_b   = (const float*)d_in[2];
  const float* w_qkv   = (const float*)d_in[3];
  const float* w_proj  = (const float*)d_in[4];
  const float* b_proj  = (const float*)d_in[5];
  const float* conv_w0 = (const float*)d_in[6];
  const float* conv_b0 = (const float*)d_in[7];
  const float* conv_w1 = (const float*)d_in[8];
  const float* conv_b1 = (const float*)d_in[9];
  const float* ln2_g   = (const float*)d_in[10];
  const float* ln2_b   = (const float*)d_in[11];
  const float* w1      = (const float*)d_in[12];
  const float* b1      = (const float*)d_in[13];
  const float* w2      = (const float*)d_in[14];
  const float* b2      = (const float*)d_in[15];
  float* out = (float*)d_out;

  unsigned short* qkv = (unsigned short*)d_ws;     // 3 planes [NTOK][128]
  unsigned short* att = qkv;                       // attention(+LePE) output in-place in q-plane
  unsigned short* wb  = qkv + 3 * PLANE;           // bf16 weights
  unsigned short* wqkvb  = wb;
  unsigned short* wprojb = wb + 49152;
  unsigned short* w1b    = wb + 65536;
  unsigned short* w2b    = wb + 131072;

  k_prep<<<dim3(192), 256, 0, stream>>>(w_qkv, w_proj, w1, w2, wb);
  k_ln_qkv<<<dim3(NTOK / 128), 256, 0, stream>>>(x, ln1_g, ln1_b, wqkvb, qkv);
  k_attn<<<dim3(512, 2, 2), 256, 0, stream>>>(qkv, conv_w0, conv_b0, conv_w1, conv_b1, att);
  k_projmlp<<<dim3(NTOK / 64), 256, 0, stream>>>(att, wprojb, b_proj, x, ln2_g, ln2_b,
                                                 w1b, w2b, b1, b2, out);
}

// Round 4
// 345.220 us; speedup vs baseline: 1.0959x; 1.0959x over previous
//
#include <hip/hip_runtime.h>
#include <cstddef>

// CSWinBlock on MI355X — round 7: round-6 structure + sched_barrier(0) hardening after every
// inline-asm waitcnt (guide rule #18: hipcc can hoist past inline-asm s_waitcnt despite
// "memory" clobber; sched_barrier(0) is the prescribed fence). k_projmlp: per-wave-private
// weight staging (each wave stages exactly the 32 ws rows it reads -> no block barrier for
// weights), software-pipelined stages (next chunk issued during current GEMM), lgkm-only
// barriers for hs/xs so weight prefetches stay in flight across barriers.
// ws layout (<= 97 MB used):
//   [0, 32MB)    q-plane  bf16 [NTOK][128]  — attention(+LePE) output written IN-PLACE here
//   [32, 64MB)   k-plane  bf16 [NTOK][128]
//   [64, 96MB)   v-plane  bf16 [NTOK][128]
//   [96MB, +384KB) bf16 weights: wqkv[49152] wproj[16384] w1[65536] w2[65536]

#define LDIM 16384
#define NTOK 131072
#define PLANE ((size_t)NTOK * 128)

typedef __attribute__((ext_vector_type(8))) short bf16x8;
typedef __attribute__((ext_vector_type(4))) float f32x4;

__device__ __forceinline__ unsigned short f2bf(float f) {
  union { float f; unsigned int i; } u; u.f = f;
  unsigned int r = u.i + 0x7fffu + ((u.i >> 16) & 1u);
  return (unsigned short)(r >> 16);
}
__device__ __forceinline__ float bflo(unsigned int u) {
  union { unsigned int i; float f; } x; x.i = u << 16; return x.f;
}
__device__ __forceinline__ float bfhi(unsigned int u) {
  union { unsigned int i; float f; } x; x.i = u & 0xffff0000u; return x.f;
}
__device__ __forceinline__ unsigned int pk(float a, float b) {
  return (unsigned)f2bf(a) | ((unsigned)f2bf(b) << 16);
}

// async 16B global->LDS (wave-uniform LDS base + lane*16)
__device__ __forceinline__ void async16(const unsigned short* g, unsigned short* l) {
  __builtin_amdgcn_global_load_lds(
      (const __attribute__((address_space(1))) unsigned int*)g,
      (__attribute__((address_space(3))) unsigned int*)l, 16, 0, 0);
}

__device__ __forceinline__ void wait_lgkm0() {
  asm volatile("s_waitcnt lgkmcnt(0)" ::: "memory");
  __builtin_amdgcn_sched_barrier(0);
}
__device__ __forceinline__ void wait_vm0() {
  asm volatile("s_waitcnt vmcnt(0)" ::: "memory");
  __builtin_amdgcn_sched_barrier(0);
}
// barrier that does NOT drain vmcnt: LDS producer/consumer only (keeps weight prefetch in flight)
__device__ __forceinline__ void barrier_lgkm() {
  asm volatile("s_waitcnt lgkmcnt(0)" ::: "memory");
  __builtin_amdgcn_s_barrier();
  __builtin_amdgcn_sched_barrier(0);
}

// swizzled tile: element (row, col) lives at row*128 + ((col/8)^(row&7))*8 + col%8
__device__ __forceinline__ bf16x8 fragS(const unsigned short* base, int row, int c) {
  return *(const bf16x8*)(base + row * 128 + ((c ^ (row & 7)) << 3));
}

// stage 128x128 bf16 tile global->LDS via async copies, swizzled layout (block-cooperative)
__device__ __forceinline__ void stageS128(const unsigned short* __restrict__ src, int rowStride,
                                          unsigned short* dst, int tid) {
  const int lane = tid & 63, wv = tid >> 6;
  #pragma unroll
  for (int i = 0; i < 8; i++) {
    const int base = i * 256 + wv * 64;     // wave-uniform chunk base
    const int f = base + lane;
    const int row = f >> 4, cs = f & 15, cg = cs ^ (row & 7);
    async16(src + (size_t)row * rowStride + (cg << 3), dst + (size_t)base * 8);
  }
}

// stage 64x128 bf16 tile global->LDS via async copies, swizzled layout (block-cooperative)
__device__ __forceinline__ void stageS64(const unsigned short* __restrict__ src,
                                         unsigned short* dst, int tid) {
  const int lane = tid & 63, wv = tid >> 6;
  #pragma unroll
  for (int i = 0; i < 4; i++) {
    const int base = i * 256 + wv * 64;
    const int f = base + lane;
    const int row = f >> 4, cs = f & 15, cg = cs ^ (row & 7);
    async16(src + (size_t)row * 128 + (cg << 3), dst + (size_t)base * 8);
  }
}

// PER-WAVE stage: 32 rows (8 KB) of a weight matrix into this wave's private ws region,
// swizzled. Only this wave reads the region -> no block barrier needed, only vmcnt.
__device__ __forceinline__ void stageW32(const unsigned short* __restrict__ src, int rowStride,
                                         unsigned short* dstRegion, int lane) {
  #pragma unroll
  for (int i = 0; i < 8; i++) {
    const int rowLocal = i * 4 + (lane >> 4);
    const int cs = lane & 15, cg = cs ^ (rowLocal & 7);
    async16(src + (size_t)rowLocal * rowStride + (cg << 3), dstRegion + i * 512);
  }
}

// 128x128x128 MFMA tile, 4 waves in 2x2
__device__ __forceinline__ void gemmS(const unsigned short* As, const unsigned short* Bs,
                                      f32x4 acc[4][4], int wm, int wn, int q, int r) {
  #pragma unroll
  for (int kc = 0; kc < 4; kc++) {
    bf16x8 a[4], b[4];
    #pragma unroll
    for (int mt = 0; mt < 4; mt++) a[mt] = fragS(As, wm * 64 + mt * 16 + r, kc * 4 + q);
    #pragma unroll
    for (int nt = 0; nt < 4; nt++) b[nt] = fragS(Bs, wn * 64 + nt * 16 + r, kc * 4 + q);
    #pragma unroll
    for (int mt = 0; mt < 4; mt++)
      #pragma unroll
      for (int nt = 0; nt < 4; nt++)
        acc[mt][nt] = __builtin_amdgcn_mfma_f32_16x16x32_bf16(a[mt], b[nt], acc[mt][nt], 0, 0, 0);
  }
}

// C frags -> swizzled LDS (reuses B tile) -> coalesced bf16 global store
__device__ __forceinline__ void storeC(f32x4 acc[4][4], unsigned short* Cs,
                                       unsigned short* __restrict__ dst, int dstStride, int tid) {
  const int wv = tid >> 6, lane = tid & 63, q = lane >> 4, r = lane & 15;
  const int wm = wv & 1, wn = wv >> 1;
  #pragma unroll
  for (int mt = 0; mt < 4; mt++)
    #pragma unroll
    for (int nt = 0; nt < 4; nt++) {
      const int col = wn * 64 + nt * 16 + r;
      #pragma unroll
      for (int rg = 0; rg < 4; rg++) {
        const int row = wm * 64 + mt * 16 + q * 4 + rg;
        Cs[row * 128 + ((((col >> 3) ^ (row & 7)) << 3) | (col & 7))] = f2bf(acc[mt][nt][rg]);
      }
    }
  __syncthreads();
  #pragma unroll
  for (int i = 0; i < 8; i++) {
    const int f = tid + i * 256;
    const int row = f >> 4, cs = f & 15, cg = cs ^ (row & 7);
    *(uint4*)(dst + (size_t)row * dstStride + (cg << 3)) = *(const uint4*)(Cs + row * 128 + cs * 8);
  }
}

// gelu tanh-approx: x*sigmoid(1.59576912*(x+0.044715x^3)) = x*rcp(1+exp2(-k*(...)))
__device__ __forceinline__ float gelu_t(float x) {
  const float y = -2.3022083f * (x + 0.044715f * x * x * x);  // -1.59576912*log2(e)*(...)
  const float p = __builtin_amdgcn_exp2f(y);
  return x * __builtin_amdgcn_rcpf(1.f + p);
}

// ================= Kernel 0: weights fp32 -> bf16 =================
__global__ void k_prep(const float* __restrict__ wq, const float* __restrict__ wp,
                       const float* __restrict__ w1, const float* __restrict__ w2,
                       unsigned short* __restrict__ wb)
{
  const int id = blockIdx.x * 256 + threadIdx.x;   // 49152 threads, 4 elems each
  const float* src; int off;
  if (id < 12288)      { src = wq; off = id; }
  else if (id < 16384) { src = wp; off = id - 12288; }
  else if (id < 32768) { src = w1; off = id - 16384; }
  else                 { src = w2; off = id - 32768; }
  const float4 v = *(const float4*)(src + (size_t)off * 4);
  uint2 u; u.x = pk(v.x, v.y); u.y = pk(v.z, v.w);
  *(uint2*)(wb + (size_t)id * 4) = u;
}

// ================= Kernel 1: LN1 + QKV GEMM (round-4 staged form) =================
__global__ __launch_bounds__(256, 2) void k_ln_qkv(
    const float* __restrict__ x, const float* __restrict__ g, const float* __restrict__ bb,
    const unsigned short* __restrict__ wqkvb, unsigned short* __restrict__ qkv)
{
  __shared__ unsigned short xs[128 * 128];
  __shared__ unsigned short ws[128 * 128];
  __shared__ float redS[128][2], redQ[128][2];
  const int tid = threadIdx.x;
  const long m0 = (long)blockIdx.x * 128;
  { // LN: 2 threads/row
    const int m = tid >> 1, hf = tid & 1;
    const float4* xg = (const float4*)(x + (size_t)(m0 + m) * 128 + hf * 64);
    float4 xv[16];
    #pragma unroll
    for (int i = 0; i < 16; i++) xv[i] = xg[i];
    float s1 = 0.f, s2 = 0.f;
    #pragma unroll
    for (int i = 0; i < 16; i++) {
      s1 += xv[i].x + xv[i].y + xv[i].z + xv[i].w;
      s2 += xv[i].x * xv[i].x + xv[i].y * xv[i].y + xv[i].z * xv[i].z + xv[i].w * xv[i].w;
    }
    redS[m][hf] = s1; redQ[m][hf] = s2;
    __syncthreads();
    const float mean = (redS[m][0] + redS[m][1]) * (1.f / 128.f);
    const float var  = (redQ[m][0] + redQ[m][1]) * (1.f / 128.f) - mean * mean;
    const float rs = rsqrtf(var + 1e-5f);
    const float4* g4 = (const float4*)(g + hf * 64);
    const float4* b4 = (const float4*)(bb + hf * 64);
    #pragma unroll
    for (int i = 0; i < 8; i++) {
      float4 v0 = xv[2 * i], v1 = xv[2 * i + 1];
      float4 g0 = g4[2 * i], g1 = g4[2 * i + 1], p0 = b4[2 * i], p1 = b4[2 * i + 1];
      uint4 u;
      u.x = pk((v0.x - mean) * rs * g0.x + p0.x, (v0.y - mean) * rs * g0.y + p0.y);
      u.y = pk((v0.z - mean) * rs * g0.z + p0.z, (v0.w - mean) * rs * g0.w + p0.w);
      u.z = pk((v1.x - mean) * rs * g1.x + p1.x, (v1.y - mean) * rs * g1.y + p1.y);
      u.w = pk((v1.z - mean) * rs * g1.z + p1.z, (v1.w - mean) * rs * g1.w + p1.w);
      const int c = hf * 8 + i;
      *(uint4*)&xs[m * 128 + ((c ^ (m & 7)) << 3)] = u;
    }
  }
  const int lane = tid & 63, q = lane >> 4, r = lane & 15;
  const int wv = tid >> 6, wm = wv & 1, wn = wv >> 1;
  for (int nc = 0; nc < 3; nc++) {
    __syncthreads();                             // xs ready / prior readout done
    stageS128(wqkvb + (size_t)nc * 16384, 128, ws, tid);
    __syncthreads();                             // ws ready
    f32x4 acc[4][4];
    #pragma unroll
    for (int a = 0; a < 4; a++)
      #pragma unroll
      for (int b = 0; b < 4; b++) acc[a][b] = f32x4{0.f, 0.f, 0.f, 0.f};
    gemmS(xs, ws, acc, wm, wn, q, r);
    __syncthreads();                             // ws reads done (reused as Cs)
    storeC(acc, ws, qkv + (size_t)nc * PLANE + (size_t)m0 * 128, 128, tid);
  }
}

// ================= Kernel 2: CSWin attention + fused LePE (in-place into q-plane) ==========
__global__ __launch_bounds__(256, 2) void k_attn(
    const unsigned short* __restrict__ qkv,
    const float* __restrict__ conv_w0, const float* __restrict__ conv_b0,
    const float* __restrict__ conv_w1, const float* __restrict__ conv_b1,
    unsigned short* __restrict__ att)
{
  __shared__ unsigned short Kt[256][40];
  __shared__ unsigned short Vt[32][264];
  __shared__ unsigned short Ps[4][64][72];
  const unsigned short* kpl = qkv + PLANE;
  const unsigned short* vpl = qkv + 2 * PLANE;
  const int t = threadIdx.x;
  const int win = blockIdx.x, head = blockIdx.y, br = blockIdx.z;
  const int bimg = win >> 6, widx = win & 63;
  const int c0 = br * 64 + head * 32;
  const int lgWs = (br == 0) ? 1 : 7;
  const int Wsm1 = (1 << lgWs) - 1;
  const long base = (long)bimg * LDIM + ((br == 0) ? widx * 2 : widx * 256);

  { // stage K + V^T (thread t = key t)
    const long tj = base + (long)(t >> lgWs) * 128 + (t & Wsm1);
    const uint4* kp = (const uint4*)(kpl + (size_t)tj * 128 + c0);
    uint4 k0v = kp[0], k1v = kp[1], k2v = kp[2], k3v = kp[3];
    *(uint4*)&Kt[t][0]  = k0v;  *(uint4*)&Kt[t][8]  = k1v;
    *(uint4*)&Kt[t][16] = k2v;  *(uint4*)&Kt[t][24] = k3v;
    const uint4* vp = (const uint4*)(vpl + (size_t)tj * 128 + c0);
    uint4 vv[4] = {vp[0], vp[1], vp[2], vp[3]};
    const unsigned short* vs = (const unsigned short*)vv;
    #pragma unroll
    for (int d = 0; d < 32; d++) Vt[d][t] = vs[d];
  }
  const int wave = t >> 6, lane = t & 63, q = lane >> 4, r = lane & 15;
  const int qbase = wave * 64;
  bf16x8 qf[4];
  #pragma unroll
  for (int mt = 0; mt < 4; mt++) {
    const int row = qbase + mt * 16 + r;
    const long tok = base + (long)(row >> lgWs) * 128 + (row & Wsm1);
    qf[mt] = *(const bf16x8*)(qkv + (size_t)tok * 128 + c0 + q * 8);
  }
  __syncthreads();

  const float factor = 0.17677669529663687f * 1.44269504088896341f;
  f32x4 Oacc[4][2];
  float psum[4][4];
  #pragma unroll
  for (int mt = 0; mt < 4; mt++) {
    Oacc[mt][0] = f32x4{0.f, 0.f, 0.f, 0.f};
    Oacc[mt][1] = f32x4{0.f, 0.f, 0.f, 0.f};
    #pragma unroll
    for (int rg = 0; rg < 4; rg++) psum[mt][rg] = 0.f;
  }

  for (int kc = 0; kc < 4; kc++) {
    bf16x8 kb[4];
    #pragma unroll
    for (int nt = 0; nt < 4; nt++) kb[nt] = *(const bf16x8*)&Kt[kc * 64 + nt * 16 + r][q * 8];
    f32x4 s[4][4];
    #pragma unroll
    for (int mt = 0; mt < 4; mt++)
      #pragma unroll
      for (int nt = 0; nt < 4; nt++) {
        f32x4 z = f32x4{0.f, 0.f, 0.f, 0.f};
        s[mt][nt] = __builtin_amdgcn_mfma_f32_16x16x32_bf16(qf[mt], kb[nt], z, 0, 0, 0);
      }
    #pragma unroll
    for (int mt = 0; mt < 4; mt++)
      #pragma unroll
      for (int nt = 0; nt < 4; nt++)
        #pragma unroll
        for (int rg = 0; rg < 4; rg++) {
          const float p = __builtin_amdgcn_exp2f(s[mt][nt][rg] * factor);   // max-free
          psum[mt][rg] += p;
          Ps[wave][mt * 16 + q * 4 + rg][nt * 16 + r] = f2bf(p);
        }
    #pragma unroll
    for (int kst = 0; kst < 2; kst++) {
      bf16x8 pa[4], vb[2];
      #pragma unroll
      for (int mt = 0; mt < 4; mt++) pa[mt] = *(const bf16x8*)&Ps[wave][mt * 16 + r][kst * 32 + q * 8];
      #pragma unroll
      for (int nto = 0; nto < 2; nto++) vb[nto] = *(const bf16x8*)&Vt[nto * 16 + r][kc * 64 + kst * 32 + q * 8];
      #pragma unroll
      for (int mt = 0; mt < 4; mt++)
        #pragma unroll
        for (int nto = 0; nto < 2; nto++)
          Oacc[mt][nto] = __builtin_amdgcn_mfma_f32_16x16x32_bf16(pa[mt], vb[nto], Oacc[mt][nto], 0, 0, 0);
    }
  }

  #pragma unroll
  for (int mt = 0; mt < 4; mt++)
    #pragma unroll
    for (int rg = 0; rg < 4; rg++) {
      float v = psum[mt][rg];
      v += __shfl_xor(v, 1); v += __shfl_xor(v, 2);
      v += __shfl_xor(v, 4); v += __shfl_xor(v, 8);
      psum[mt][rg] = __builtin_amdgcn_rcpf(v);
    }

  // ---- fused LePE: depthwise 3x3 over the window, V already staged in Vt ----
  const float* cw = br ? conv_w1 : conv_w0;
  const float* cb = br ? conv_b1 : conv_b0;
  float wle[2][9], ble[2];
  #pragma unroll
  for (int nto = 0; nto < 2; nto++) {
    const int ch = head * 32 + nto * 16 + r;      // channel within branch (0..63)
    ble[nto] = cb[ch];
    #pragma unroll
    for (int tp = 0; tp < 9; tp++) wle[nto][tp] = cw[ch * 9 + tp];
  }
  const int WsW = 1 << lgWs;          // 2 (br0) or 128 (br1)
  const int HsW = 256 >> lgWs;        // 128 (br0) or 2 (br1)

  #pragma unroll
  for (int mt = 0; mt < 4; mt++)
    #pragma unroll
    for (int rg = 0; rg < 4; rg++) {
      const int row = qbase + mt * 16 + q * 4 + rg;      // window token 0..255
      const int ii = row >> lgWs, jj = row & Wsm1;
      const long tok = base + (long)ii * 128 + jj;
      float lep0 = ble[0], lep1 = ble[1];
      #pragma unroll
      for (int di = -1; di <= 1; di++) {
        if ((unsigned)(ii + di) >= (unsigned)HsW) continue;
        #pragma unroll
        for (int dj = -1; dj <= 1; dj++) {
          if ((unsigned)(jj + dj) >= (unsigned)WsW) continue;
          const int nb = row + di * WsW + dj;            // neighbor window token
          const int tap = (di + 1) * 3 + (dj + 1);
          lep0 = fmaf(bflo(Vt[r][nb]),      wle[0][tap], lep0);
          lep1 = fmaf(bflo(Vt[16 + r][nb]), wle[1][tap], lep1);
        }
      }
      const float pr = psum[mt][rg];
      att[(size_t)tok * 128 + c0 + r]      = f2bf(Oacc[mt][0][rg] * pr + lep0);
      att[(size_t)tok * 128 + c0 + 16 + r] = f2bf(Oacc[mt][1][rg] * pr + lep1);
    }
}

// ========== Kernel 3: fused proj + residual + LN2 + FFN1 + GELU + FFN2 + residual ==========
// Per-wave-private weight staging: wave wv only reads ws rows [wv*32, wv*32+32) -> it stages
// them itself; no block barrier for weights, only per-wave vmcnt. Next chunk's stage is
// issued during the current GEMM (pipelined); hs/xs barriers are lgkm-only so the weight
// prefetch stays in flight across them.
__global__ __launch_bounds__(256, 2) void k_projmlp(
    const unsigned short* __restrict__ att, const unsigned short* __restrict__ wprojb,
    const float* __restrict__ b_proj, const float* __restrict__ x,
    const float* __restrict__ g, const float* __restrict__ bb,
    const unsigned short* __restrict__ w1b, const unsigned short* __restrict__ w2b,
    const float* __restrict__ b1, const float* __restrict__ b2,
    float* __restrict__ out)
{
  __shared__ unsigned short hs[64 * 128];   // att tile (proj A), later gelu(h)
  __shared__ unsigned short xs[64 * 128];   // LN2 output (bf16, swizzled)
  __shared__ unsigned short ws[128 * 128];  // 4 x per-wave 32-row weight regions
  __shared__ float redS[64][4], redQ[64][4];
  const int tid = threadIdx.x;
  const long m0 = (long)blockIdx.x * 64;
  const int lane = tid & 63, q = lane >> 4, r = lane & 15, wv = tid >> 6;
  unsigned short* wsW = ws + (size_t)wv * 32 * 128;   // this wave's private region

  stageS64(att + (size_t)m0 * 128, hs, tid);
  stageW32(wprojb + (size_t)(wv * 32) * 128, 128, wsW, lane);

  // hoisted residual/param loads — independent of the staging above
  float xv[4][2][4];
  #pragma unroll
  for (int mt = 0; mt < 4; mt++)
    #pragma unroll
    for (int nt = 0; nt < 2; nt++) {
      const int col = wv * 32 + nt * 16 + r;
      #pragma unroll
      for (int rg = 0; rg < 4; rg++)
        xv[mt][nt][rg] = x[(size_t)(m0 + mt * 16 + q * 4 + rg) * 128 + col];
    }
  float bpv[2], gv[2], bv2[2], b1v[4][2], b2v[2];
  #pragma unroll
  for (int nt = 0; nt < 2; nt++) {
    const int col = wv * 32 + nt * 16 + r;
    bpv[nt] = b_proj[col]; gv[nt] = g[col]; bv2[nt] = bb[col]; b2v[nt] = b2[col];
    #pragma unroll
    for (int nc = 0; nc < 4; nc++) b1v[nc][nt] = b1[nc * 128 + col];
  }
  __syncthreads();                                 // full drain: hs + wproj landed, all waves

  // ---- proj GEMM: rows mt*16+q*4+rg (0..63), cols wv*32+nt*16+r
  f32x4 xres[4][2];
  #pragma unroll
  for (int mt = 0; mt < 4; mt++) { xres[mt][0] = f32x4{0.f,0.f,0.f,0.f}; xres[mt][1] = f32x4{0.f,0.f,0.f,0.f}; }
  #pragma unroll
  for (int kc = 0; kc < 4; kc++) {
    bf16x8 a[4], b[2];
    #pragma unroll
    for (int mt = 0; mt < 4; mt++) a[mt] = fragS(hs, mt * 16 + r, kc * 4 + q);
    #pragma unroll
    for (int nt = 0; nt < 2; nt++) b[nt] = fragS(ws, wv * 32 + nt * 16 + r, kc * 4 + q);
    #pragma unroll
    for (int mt = 0; mt < 4; mt++)
      #pragma unroll
      for (int nt = 0; nt < 2; nt++)
        xres[mt][nt] = __builtin_amdgcn_mfma_f32_16x16x32_bf16(a[mt], b[nt], xres[mt][nt], 0, 0, 0);
  }
  // prefetch w1[0] into this wave's region (covered by LN2 phase)
  wait_lgkm0();
  stageW32(w1b + (size_t)(wv * 32) * 128, 128, wsW, lane);

  // residual add
  #pragma unroll
  for (int mt = 0; mt < 4; mt++)
    #pragma unroll
    for (int nt = 0; nt < 2; nt++)
      #pragma unroll
      for (int rg = 0; rg < 4; rg++)
        xres[mt][nt][rg] += xv[mt][nt][rg] + bpv[nt];

  // ---- LN2 stats: per-row sums (wave covers 32 cols -> shfl over r, cross-wave via LDS)
  #pragma unroll
  for (int mt = 0; mt < 4; mt++)
    #pragma unroll
    for (int rg = 0; rg < 4; rg++) {
      float s1 = xres[mt][0][rg] + xres[mt][1][rg];
      float s2 = xres[mt][0][rg] * xres[mt][0][rg] + xres[mt][1][rg] * xres[mt][1][rg];
      s1 += __shfl_xor(s1, 1); s1 += __shfl_xor(s1, 2); s1 += __shfl_xor(s1, 4); s1 += __shfl_xor(s1, 8);
      s2 += __shfl_xor(s2, 1); s2 += __shfl_xor(s2, 2); s2 += __shfl_xor(s2, 4); s2 += __shfl_xor(s2, 8);
      if (r == 0) { const int row = mt * 16 + q * 4 + rg; redS[row][wv] = s1; redQ[row][wv] = s2; }
    }
  barrier_lgkm();                                  // red ready (w1[0] stage stays in flight)
  #pragma unroll
  for (int mt = 0; mt < 4; mt++)
    #pragma unroll
    for (int rg = 0; rg < 4; rg++) {
      const int row = mt * 16 + q * 4 + rg;
      const float s1 = redS[row][0] + redS[row][1] + redS[row][2] + redS[row][3];
      const float s2 = redQ[row][0] + redQ[row][1] + redQ[row][2] + redQ[row][3];
      const float mean = s1 * (1.f / 128.f);
      const float var  = s2 * (1.f / 128.f) - mean * mean;
      const float rs = rsqrtf(var + 1e-5f);
      #pragma unroll
      for (int nt = 0; nt < 2; nt++) {
        const int col = wv * 32 + nt * 16 + r;
        const float v = (xres[mt][nt][rg] - mean) * rs * gv[nt] + bv2[nt];
        xs[row * 128 + ((((col >> 3) ^ (row & 7)) << 3) | (col & 7))] = f2bf(v);
      }
    }
  barrier_lgkm();                                  // xs ready

  // ---- MLP: 4 Dff chunks of 128; pipelined per-wave weight staging
  f32x4 oacc[4][2];
  #pragma unroll
  for (int mt = 0; mt < 4; mt++) { oacc[mt][0] = f32x4{0.f,0.f,0.f,0.f}; oacc[mt][1] = f32x4{0.f,0.f,0.f,0.f}; }

  for (int nc = 0; nc < 4; nc++) {
    // w1[nc] was staged during the previous GEMM2 (or LN2 for nc=0)
    wait_vm0();
    bf16x8 b1f[4][2];
    #pragma unroll
    for (int kc = 0; kc < 4; kc++)
      #pragma unroll
      for (int nt = 0; nt < 2; nt++)
        b1f[kc][nt] = fragS(ws, wv * 32 + nt * 16 + r, kc * 4 + q);
    wait_lgkm0();
    stageW32(w2b + (size_t)(wv * 32) * 512 + nc * 128, 512, wsW, lane);   // w2[nc] in flight
    // GEMM1: A from xs, B from registers
    f32x4 h[4][2];
    #pragma unroll
    for (int mt = 0; mt < 4; mt++) { h[mt][0] = f32x4{0.f,0.f,0.f,0.f}; h[mt][1] = f32x4{0.f,0.f,0.f,0.f}; }
    #pragma unroll
    for (int kc = 0; kc < 4; kc++) {
      bf16x8 a[4];
      #pragma unroll
      for (int mt = 0; mt < 4; mt++) a[mt] = fragS(xs, mt * 16 + r, kc * 4 + q);
      #pragma unroll
      for (int mt = 0; mt < 4; mt++)
        #pragma unroll
        for (int nt = 0; nt < 2; nt++)
          h[mt][nt] = __builtin_amdgcn_mfma_f32_16x16x32_bf16(a[mt], b1f[kc][nt], h[mt][nt], 0, 0, 0);
    }
    barrier_lgkm();                                // A: prior hs reads done everywhere
    // gelu -> hs (this wave's 32-col strip)
    #pragma unroll
    for (int mt = 0; mt < 4; mt++)
      #pragma unroll
      for (int nt = 0; nt < 2; nt++) {
        const int col = wv * 32 + nt * 16 + r;
        const float bv = b1v[nc][nt];
        #pragma unroll
        for (int rg = 0; rg < 4; rg++) {
          const int rw = mt * 16 + q * 4 + rg;
          hs[rw * 128 + ((((col >> 3) ^ (rw & 7)) << 3) | (col & 7))] = f2bf(gelu_t(h[mt][nt][rg] + bv));
        }
      }
    barrier_lgkm();                                // B: hs = gelu(h) ready
    // w2[nc] landed by now (covered by GEMM1 + gelu)
    wait_vm0();
    bf16x8 b2f[4][2];
    #pragma unroll
    for (int kc = 0; kc < 4; kc++)
      #pragma unroll
      for (int nt = 0; nt < 2; nt++)
        b2f[kc][nt] = fragS(ws, wv * 32 + nt * 16 + r, kc * 4 + q);
    wait_lgkm0();
    if (nc < 3)
      stageW32(w1b + (size_t)((nc + 1) * 128 + wv * 32) * 128, 128, wsW, lane);  // w1[nc+1] in flight
    // GEMM2: A from hs, B from registers
    #pragma unroll
    for (int kc = 0; kc < 4; kc++) {
      bf16x8 a[4];
      #pragma unroll
      for (int mt = 0; mt < 4; mt++) a[mt] = fragS(hs, mt * 16 + r, kc * 4 + q);
      #pragma unroll
      for (int mt = 0; mt < 4; mt++)
        #pragma unroll
        for (int nt = 0; nt < 2; nt++)
          oacc[mt][nt] = __builtin_amdgcn_mfma_f32_16x16x32_bf16(a[mt], b2f[kc][nt], oacc[mt][nt], 0, 0, 0);
    }
  }
  // ---- epilogue: out = xres + b2 + mlp  (single write, no out-read)
  #pragma unroll
  for (int mt = 0; mt < 4; mt++)
    #pragma unroll
    for (int nt = 0; nt < 2; nt++) {
      const float bv = b2v[nt];
      const int col = wv * 32 + nt * 16 + r;
      #pragma unroll
      for (int rg = 0; rg < 4; rg++) {
        const size_t idx = (size_t)(m0 + mt * 16 + q * 4 + rg) * 128 + col;
        out[idx] = xres[mt][nt][rg] + bv + oacc[mt][nt][rg];
      }
    }
}

extern "C" void kernel_launch(void* const* d_in, const int* in_sizes, int n_in,
                              void* d_out, int out_size, void* d_ws, size_t ws_size,
                              hipStream_t stream) {
  const float* x       = (const float*)d_in[0];
  const float* ln1_g   = (const float*)d_in[1];
  const float* ln1_b   = (const float*)d_in[2];
  const float* w_qkv   = (const float*)d_in[3];
  const float* w_proj  = (const float*)d_in[4];
  const float* b_proj  = (const float*)d_in[5];
  const float* conv_w0 = (const float*)d_in[6];
  const float* conv_b0 = (const float*)d_in[7];
  const float* conv_w1 = (const float*)d_in[8];
  const float* conv_b1 = (const float*)d_in[9];
  const float* ln2_g   = (const float*)d_in[10];
  const float* ln2_b   = (const float*)d_in[11];
  const float* w1      = (const float*)d_in[12];
  const float* b1      = (const float*)d_in[13];
  const float* w2      = (const float*)d_in[14];
  const float* b2      = (const float*)d_in[15];
  float* out = (float*)d_out;

  unsigned short* qkv = (unsigned short*)d_ws;     // 3 planes [NTOK][128]
  unsigned short* att = qkv;                       // attention(+LePE) output in-place in q-plane
  unsigned short* wb  = qkv + 3 * PLANE;           // bf16 weights
  unsigned short* wqkvb  = wb;
  unsigned short* wprojb = wb + 49152;
  unsigned short* w1b    = wb + 65536;
  unsigned short* w2b    = wb + 131072;

  k_prep<<<dim3(192), 256, 0, stream>>>(w_qkv, w_proj, w1, w2, wb);
  k_ln_qkv<<<dim3(NTOK / 128), 256, 0, stream>>>(x, ln1_g, ln1_b, wqkvb, qkv);
  k_attn<<<dim3(512, 2, 2), 256, 0, stream>>>(qkv, conv_w0, conv_b0, conv_w1, conv_b1, att);
  k_projmlp<<<dim3(NTOK / 64), 256, 0, stream>>>(att, wprojb, b_proj, x, ln2_g, ln2_b,
                                                 w1b, w2b, b1, b2, out);
}